// Round 2
// baseline (40.185 us; speedup 1.0000x reference)
//
#include <hip/hip_runtime.h>
#include <math.h>

#define NB 32
#define NA 5
#define NC 13
#define NHH 76
#define NWW 76
#define NT 50
#define CH (19 + NC)              // 32 channels per anchor
#define CELLS (NHH * NWW)         // 5776
#define NBA (NB * NA)             // 160 (b,a) slabs
#define V4_PER_SLAB (CELLS / 4)   // 1444 float4 per conf slab
#define SWEEP_BX 6                // 6*256 = 1536 >= 1444
#define SWEEP_BLOCKS (SWEEP_BX * NBA)  // 960

#define OBJ_SCALE 5.0f
#define TH_ 80.0f
#define SHARP_ 2.0f
#define IMW_ 640.0f
#define IMH_ 480.0f

// ws layout:
//   corr    : double[NB]            @ 0       (256 B)
//   partials: double[SWEEP_BLOCKS]  @ 256     (7680 B)
//   counter : int                   @ 7936
#define WS_PART_OFF 256
#define WS_CNT_OFF  7936

__device__ __forceinline__ float sigmoidf_(float x) {
    return 1.0f / (1.0f + expf(-x));
}

// One block per batch. Resolves winner targets, computes the sparse
// correction sum for this batch, zeroes the ticket counter.
__global__ void targets_kernel(const float* __restrict__ outp,
                               const float* __restrict__ tgt,
                               double* __restrict__ corr,
                               int* __restrict__ counter) {
    int b = blockIdx.x;
    int t = threadIdx.x;
    if (b == 0 && t == 0) *counter = 0;   // runs before sweep (same stream)

    __shared__ int sgi[NT], sgj[NT], snz[NT], svalid[NT];

    if (t < NT) {
        const float* tg = tgt + (size_t)(b * NT + t) * 21;
        float cx = tg[1];
        float cy = tg[2];
        sgi[t] = (int)floorf(cx * (float)NWW);
        sgj[t] = (int)floorf(cy * (float)NHH);
        snz[t] = (cx != 0.0f) ? 1 : 0;
    }
    __syncthreads();
    if (t < NT) {
        int v = 1;
        for (int k = 0; k <= t; ++k) v &= snz[k];   // cumprod of (x != 0)
        svalid[t] = v;
    }
    __syncthreads();

    double local = 0.0;
    if (t < NT) {
        int gi = sgi[t], gj = sgj[t];
        bool inb = (gi >= 0 && gi < NWW && gj >= 0 && gj < NHH);
        bool win = svalid[t] && inb;
        if (win) {
            // last valid target hitting the same cell wins (JAX scatter order)
            for (int k2 = t + 1; k2 < NT; ++k2) {
                if (svalid[k2] && sgi[k2] == gi && sgj[k2] == gj) { win = false; break; }
            }
        }
        if (win) {
            const float* tg = tgt + (size_t)(b * NT + t) * 21;
            int cell = gj * NWW + gi;
            const float* base = outp + (size_t)b * NA * CH * CELLS;  // anchor 0

            float v[19];
            #pragma unroll
            for (int c = 0; c < 19; ++c) v[c] = base[(size_t)c * CELLS + cell];
            float s0 = sigmoidf_(v[0]);
            float s1 = sigmoidf_(v[1]);
            float confv = sigmoidf_(v[18]);

            // conf_t (winner is in-bounds, so clamped == raw indices)
            const float denom = expf(SHARP_) - 1.0f + 1e-5f;
            float ssum = 0.0f;
            #pragma unroll
            for (int k = 0; k < 9; ++k) {
                float vx = (k == 0) ? s0 : v[2 * k];
                float vy = (k == 0) ? s1 : v[2 * k + 1];
                float px = (vx + (float)gi) / (float)NWW;
                float py = (vy + (float)gj) / (float)NHH;
                float dx = (tg[1 + 2 * k] - px) * IMW_;
                float dy = (tg[2 + 2 * k] - py) * IMH_;
                float dn = sqrtf(dx * dx + dy * dy);
                if (dn < TH_) ssum += expf(SHARP_ * (1.0f - dn / TH_)) - 1.0f;
            }
            float conf_t = (ssum / 9.0f) / denom;

            // coord term
            float cs = 0.0f;
            #pragma unroll
            for (int k = 0; k < 9; ++k) {
                float tvx = tg[1 + 2 * k] * (float)NWW - (float)gi;
                float tvy = tg[2 + 2 * k] * (float)NHH - (float)gj;
                float dx = ((k == 0) ? s0 : v[2 * k]) - tvx;
                float dy = ((k == 0) ? s1 : v[2 * k + 1]) - tvy;
                cs += dx * dx + dy * dy;
            }

            float dc = confv - conf_t;
            local = 0.5 * (double)(OBJ_SCALE * dc * dc - confv * confv + cs);
        }
    }

    __shared__ double sdata[64];
    sdata[t] = local;
    __syncthreads();
    for (int s = 32; s > 0; s >>= 1) {
        if (t < s) sdata[t] += sdata[t + s];
        __syncthreads();
    }
    if (t == 0) corr[b] = sdata[0];
}

// Dense sweep over the conf channel only: sum 0.5*sigmoid(x)^2 over all
// (b,a,cells). Last finishing block folds partials + corr into out[0].
__global__ void sweep_kernel(const float* __restrict__ outp,
                             const double* __restrict__ corr,
                             double* __restrict__ partials,
                             int* __restrict__ counter,
                             float* __restrict__ out) {
    int ba = blockIdx.y;
    int v = blockIdx.x * 256 + threadIdx.x;
    double acc = 0.0;
    if (v < V4_PER_SLAB) {
        const float4* slab =
            (const float4*)(outp + ((size_t)ba * CH + 18) * CELLS);
        float4 q = slab[v];
        float a0 = sigmoidf_(q.x), a1 = sigmoidf_(q.y);
        float a2 = sigmoidf_(q.z), a3 = sigmoidf_(q.w);
        acc = 0.5 * (double)(a0 * a0 + a1 * a1 + a2 * a2 + a3 * a3);
    }

    __shared__ double sdata[256];
    sdata[threadIdx.x] = acc;
    __syncthreads();
    for (int s = 128; s > 0; s >>= 1) {
        if (threadIdx.x < s) sdata[threadIdx.x] += sdata[threadIdx.x + s];
        __syncthreads();
    }
    int bid = ba * SWEEP_BX + blockIdx.x;
    __shared__ bool amLast;
    if (threadIdx.x == 0) {
        partials[bid] = sdata[0];
        __threadfence();
        int ticket = atomicAdd(counter, 1);
        amLast = (ticket == SWEEP_BLOCKS - 1);
    }
    __syncthreads();

    if (amLast) {
        double facc = 0.0;
        for (int i = threadIdx.x; i < SWEEP_BLOCKS; i += 256) facc += partials[i];
        if (threadIdx.x < NB) facc += corr[threadIdx.x];
        sdata[threadIdx.x] = facc;
        __syncthreads();
        for (int s = 128; s > 0; s >>= 1) {
            if (threadIdx.x < s) sdata[threadIdx.x] += sdata[threadIdx.x + s];
            __syncthreads();
        }
        if (threadIdx.x == 0) {
            out[0] = (float)sdata[0];
            *counter = 0;   // leave clean for next replay (also re-zeroed by targets_kernel)
        }
    }
}

extern "C" void kernel_launch(void* const* d_in, const int* in_sizes, int n_in,
                              void* d_out, int out_size, void* d_ws, size_t ws_size,
                              hipStream_t stream) {
    const float* outp = (const float*)d_in[0];
    const float* tgt  = (const float*)d_in[1];
    float* out = (float*)d_out;
    char* ws = (char*)d_ws;

    double* corr     = (double*)ws;
    double* partials = (double*)(ws + WS_PART_OFF);
    int*    counter  = (int*)(ws + WS_CNT_OFF);

    targets_kernel<<<NB, 64, 0, stream>>>(outp, tgt, corr, counter);
    sweep_kernel<<<dim3(SWEEP_BX, NBA), 256, 0, stream>>>(outp, corr, partials,
                                                          counter, out);
}

// Round 3
// 20.254 us; speedup vs baseline: 1.9841x; 1.9841x over previous
//
#include <hip/hip_runtime.h>
#include <math.h>

#define NB 32
#define NA 5
#define NC 13
#define NHH 76
#define NWW 76
#define NT 50
#define CH (19 + NC)              // 32 channels per anchor
#define CELLS (NHH * NWW)         // 5776
#define NBA (NB * NA)             // 160 (b,a) slabs
#define V4_PER_SLAB (CELLS / 4)   // 1444 float4 per conf slab
#define TOTAL_V4 (NBA * V4_PER_SLAB)  // 231040
#define SWEEP_BLOCKS 512
#define GRID_BLOCKS (SWEEP_BLOCKS + NB)   // 544
#define NPART GRID_BLOCKS

#define OBJ_SCALE 5.0f
#define TH_ 80.0f
#define SHARP_ 2.0f
#define IMW_ 640.0f
#define IMH_ 480.0f

__device__ __forceinline__ float sigmoidf_(float x) {
    return 1.0f / (1.0f + expf(-x));
}

// Fused kernel: blocks [0,512) sweep the conf channel (dense 0.5*conf^2 sum),
// blocks [512,544) compute the per-batch sparse correction:
//   sum over winner cells of 0.5*(OBJ*(conf-conf_t)^2 - conf^2 + coord_sq)
__global__ void main_kernel(const float* __restrict__ outp,
                            const float* __restrict__ tgt,
                            double* __restrict__ partials) {
    int bid = blockIdx.x;
    int tid = threadIdx.x;

    if (bid < SWEEP_BLOCKS) {
        // ---- dense conf sweep, grid-stride over float4s ----
        double acc = 0.0;
        for (int idx = bid * 256 + tid; idx < TOTAL_V4; idx += SWEEP_BLOCKS * 256) {
            int ba = idx / V4_PER_SLAB;
            int r  = idx - ba * V4_PER_SLAB;
            const float4* slab =
                (const float4*)(outp + ((size_t)ba * CH + 18) * CELLS);
            float4 q = slab[r];
            float a0 = sigmoidf_(q.x), a1 = sigmoidf_(q.y);
            float a2 = sigmoidf_(q.z), a3 = sigmoidf_(q.w);
            acc += 0.5 * (double)(a0 * a0 + a1 * a1 + a2 * a2 + a3 * a3);
        }
        __shared__ double sdata[256];
        sdata[tid] = acc;
        __syncthreads();
        for (int s = 128; s > 0; s >>= 1) {
            if (tid < s) sdata[tid] += sdata[tid + s];
            __syncthreads();
        }
        if (tid == 0) partials[bid] = sdata[0];
    } else {
        // ---- per-batch sparse correction ----
        int b = bid - SWEEP_BLOCKS;
        __shared__ int sgi[NT], sgj[NT], snz[NT], svalid[NT];

        if (tid < NT) {
            const float* tg = tgt + (size_t)(b * NT + tid) * 21;
            float cx = tg[1];
            float cy = tg[2];
            sgi[tid] = (int)floorf(cx * (float)NWW);
            sgj[tid] = (int)floorf(cy * (float)NHH);
            snz[tid] = (cx != 0.0f) ? 1 : 0;
        }
        __syncthreads();
        if (tid < NT) {
            int v = 1;
            for (int k = 0; k <= tid; ++k) v &= snz[k];   // cumprod of (x != 0)
            svalid[tid] = v;
        }
        __syncthreads();

        double local = 0.0;
        if (tid < NT) {
            int gi = sgi[tid], gj = sgj[tid];
            bool inb = (gi >= 0 && gi < NWW && gj >= 0 && gj < NHH);
            bool win = svalid[tid] && inb;
            if (win) {
                // last valid target hitting the same cell wins (JAX scatter order)
                for (int k2 = tid + 1; k2 < NT; ++k2) {
                    if (svalid[k2] && sgi[k2] == gi && sgj[k2] == gj) { win = false; break; }
                }
            }
            if (win) {
                const float* tg = tgt + (size_t)(b * NT + tid) * 21;
                int cell = gj * NWW + gi;
                const float* base = outp + (size_t)b * NA * CH * CELLS;  // anchor 0

                float v[19];
                #pragma unroll
                for (int c = 0; c < 19; ++c) v[c] = base[(size_t)c * CELLS + cell];
                float s0 = sigmoidf_(v[0]);
                float s1 = sigmoidf_(v[1]);
                float confv = sigmoidf_(v[18]);

                const float denom = expf(SHARP_) - 1.0f + 1e-5f;
                float ssum = 0.0f;
                #pragma unroll
                for (int k = 0; k < 9; ++k) {
                    float vx = (k == 0) ? s0 : v[2 * k];
                    float vy = (k == 0) ? s1 : v[2 * k + 1];
                    float px = (vx + (float)gi) / (float)NWW;
                    float py = (vy + (float)gj) / (float)NHH;
                    float dx = (tg[1 + 2 * k] - px) * IMW_;
                    float dy = (tg[2 + 2 * k] - py) * IMH_;
                    float dn = sqrtf(dx * dx + dy * dy);
                    if (dn < TH_) ssum += expf(SHARP_ * (1.0f - dn / TH_)) - 1.0f;
                }
                float conf_t = (ssum / 9.0f) / denom;

                float cs = 0.0f;
                #pragma unroll
                for (int k = 0; k < 9; ++k) {
                    float tvx = tg[1 + 2 * k] * (float)NWW - (float)gi;
                    float tvy = tg[2 + 2 * k] * (float)NHH - (float)gj;
                    float dx = ((k == 0) ? s0 : v[2 * k]) - tvx;
                    float dy = ((k == 0) ? s1 : v[2 * k + 1]) - tvy;
                    cs += dx * dx + dy * dy;
                }

                float dc = confv - conf_t;
                local = 0.5 * (double)(OBJ_SCALE * dc * dc - confv * confv + cs);
            }
        }

        __shared__ double sdata2[256];
        sdata2[tid] = local;
        __syncthreads();
        for (int s = 128; s > 0; s >>= 1) {
            if (tid < s) sdata2[tid] += sdata2[tid + s];
            __syncthreads();
        }
        if (tid == 0) partials[bid] = sdata2[0];
    }
}

__global__ void final_kernel(const double* __restrict__ partials,
                             float* __restrict__ out) {
    __shared__ double sdata[256];
    double acc = 0.0;
    for (int i = threadIdx.x; i < NPART; i += 256) acc += partials[i];
    sdata[threadIdx.x] = acc;
    __syncthreads();
    for (int s = 128; s > 0; s >>= 1) {
        if (threadIdx.x < s) sdata[threadIdx.x] += sdata[threadIdx.x + s];
        __syncthreads();
    }
    if (threadIdx.x == 0) out[0] = (float)sdata[0];
}

extern "C" void kernel_launch(void* const* d_in, const int* in_sizes, int n_in,
                              void* d_out, int out_size, void* d_ws, size_t ws_size,
                              hipStream_t stream) {
    const float* outp = (const float*)d_in[0];
    const float* tgt  = (const float*)d_in[1];
    float* out = (float*)d_out;
    double* partials = (double*)d_ws;

    main_kernel<<<GRID_BLOCKS, 256, 0, stream>>>(outp, tgt, partials);
    final_kernel<<<1, 256, 0, stream>>>(partials, out);
}